// Round 6
// baseline (176.503 us; speedup 1.0000x reference)
//
#include <hip/hip_runtime.h>

#define BATCH 4096
#define SEQT  512
#define HID   32

typedef _Float16 f16;
typedef _Float16 f16x4 __attribute__((ext_vector_type(4)));
typedef float    f32x4 __attribute__((ext_vector_type(4)));

// Legacy K=16 MFMA builtins use the NO-underscore spelling (16x16x16f16);
// only gfx950-new 2xK shapes have the underscore. Round-5 compile error
// confirmed: '..._f16' undeclared, compiler suggests '...16f16'.
#define MFMA16(a, b, c) __builtin_amdgcn_mfma_f32_16x16x16f16((a), (b), (c), 0, 0, 0)

#if __has_builtin(__builtin_amdgcn_exp2f)
#define FAST_EXP2(x) __builtin_amdgcn_exp2f(x)
#else
#define FAST_EXP2(x) exp2f(x)
#endif
#if __has_builtin(__builtin_amdgcn_rcpf)
#define FAST_RCP(x) __builtin_amdgcn_rcpf(x)
#else
#define FAST_RCP(x) (1.0f / (x))
#endif

#define BCI(f) __builtin_bit_cast(int, (f))
#define BCF(i) __builtin_bit_cast(float, (i))

// MFMA-driven RNN: one wave owns 16 sequences. h-state [32 hid x 16 seq] lives
// in MFMA accumulator layout. Per step, H_new = tanh(W_hh*H + wih*x + bias) is:
//   4x v_mfma_f32_16x16x16_f16 (W halves x K halves) + 8-elem tanh + f16 pack.
// Layout identity (classic 16x16x16 shape): D: col=lane&15, row=4*(lane>>4)+r;
// B: col=lane&15, k=4*(lane>>4)+e. Identical index maps => D_half_m packs
// DIRECTLY into the B operand for k-half m. NO cross-lane remap in the
// recurrence: the serial chain is mfma -> mfma -> tanh -> pack -> mfma.
// W_hh/W_ih/biases are pre-scaled by 2*log2(e) so tanh = 1-2/(exp2(D)+1) needs
// no per-step multiply. Output Linear(32->1): 8 fma partials + ds_bpermute
// q-reduce (lane^16, lane^32); results kept in 16 static regs, flushed as 4x
// dwordx4 per 16-step chunk by q==0 lanes. x register-resident, double-buffered.
__global__ __launch_bounds__(64, 1) void rnn_kernel(
    const float* __restrict__ x,      // [B, T]
    const float* __restrict__ h0,     // [B, H]
    const float* __restrict__ W_ih,   // [H]
    const float* __restrict__ b_ih,   // [H]
    const float* __restrict__ W_hh,   // [H, H] row-major
    const float* __restrict__ b_hh,   // [H]
    const float* __restrict__ W_out,  // [H]
    const float* __restrict__ b_out,  // [1]
    float* __restrict__ out)          // [B*T] outs, then [B*H] hT
{
    const int lane = threadIdx.x & 63;
    const int c    = lane & 15;            // seq column within tile
    const int q    = lane >> 4;            // 4-row group
    const int seq  = blockIdx.x * 16 + c;

    const float SC = 2.8853900817779268f;  // 2*log2(e), folded into W/b

    // ---- A fragments: A[m][kh], row = 16m + (lane&15), k = 16kh + 4q + e ----
    f16x4 A00, A01, A10, A11;
    {
        const float4 w00 = *reinterpret_cast<const float4*>(W_hh + c * HID + 4 * q);
        const float4 w01 = *reinterpret_cast<const float4*>(W_hh + c * HID + 16 + 4 * q);
        const float4 w10 = *reinterpret_cast<const float4*>(W_hh + (16 + c) * HID + 4 * q);
        const float4 w11 = *reinterpret_cast<const float4*>(W_hh + (16 + c) * HID + 16 + 4 * q);
        A00 = f16x4{(f16)(SC * w00.x), (f16)(SC * w00.y), (f16)(SC * w00.z), (f16)(SC * w00.w)};
        A01 = f16x4{(f16)(SC * w01.x), (f16)(SC * w01.y), (f16)(SC * w01.z), (f16)(SC * w01.w)};
        A10 = f16x4{(f16)(SC * w10.x), (f16)(SC * w10.y), (f16)(SC * w10.z), (f16)(SC * w10.w)};
        A11 = f16x4{(f16)(SC * w11.x), (f16)(SC * w11.y), (f16)(SC * w11.z), (f16)(SC * w11.w)};
    }

    // ---- per-lane params: i = m*4 + r  <->  hidden h = 16m + 4q + r ----
    float wihs[8], biass[8], wos[8];
    #pragma unroll
    for (int m = 0; m < 2; ++m)
        #pragma unroll
        for (int r = 0; r < 4; ++r) {
            const int h = 16 * m + 4 * q + r;
            wihs[m * 4 + r]  = SC * W_ih[h];
            biass[m * 4 + r] = SC * (b_ih[h] + b_hh[h]);
            wos[m * 4 + r]   = W_out[h];
        }
    const float bout = b_out[0];

    // ---- B fragments seeded from h0: k = 16kh + 4q + e, col = c ----
    f16x4 Blo, Bhi;
    {
        const float4 lo = *reinterpret_cast<const float4*>(h0 + (size_t)seq * HID + 4 * q);
        const float4 hi = *reinterpret_cast<const float4*>(h0 + (size_t)seq * HID + 16 + 4 * q);
        Blo = f16x4{(f16)lo.x, (f16)lo.y, (f16)lo.z, (f16)lo.w};
        Bhi = f16x4{(f16)hi.x, (f16)hi.y, (f16)hi.z, (f16)hi.w};
    }

    const float* xg = x + (size_t)seq * SEQT;
    float*       og = out + (size_t)seq * SEQT;

    const int ix16 = (lane ^ 16) << 2;
    const int ix32 = (lane ^ 32) << 2;

    float hn[8];      // f32 post-tanh state (persists for hT)
    float os[16];     // per-chunk output stash (static indexing only)

#define STEP(T2, XC) do {                                                     \
    f32x4 C0, C1;                                                             \
    C0[0] = fmaf((XC), wihs[0], biass[0]);                                    \
    C0[1] = fmaf((XC), wihs[1], biass[1]);                                    \
    C0[2] = fmaf((XC), wihs[2], biass[2]);                                    \
    C0[3] = fmaf((XC), wihs[3], biass[3]);                                    \
    C1[0] = fmaf((XC), wihs[4], biass[4]);                                    \
    C1[1] = fmaf((XC), wihs[5], biass[5]);                                    \
    C1[2] = fmaf((XC), wihs[6], biass[6]);                                    \
    C1[3] = fmaf((XC), wihs[7], biass[7]);                                    \
    f32x4 D0 = MFMA16(A00, Blo, C0);                                          \
    f32x4 D1 = MFMA16(A10, Blo, C1);                                          \
    D0 = MFMA16(A01, Bhi, D0);                                                \
    D1 = MFMA16(A11, Bhi, D1);                                                \
    float o = 0.0f;                                                           \
    _Pragma("unroll")                                                         \
    for (int r = 0; r < 4; ++r) {                                             \
        const float e0 = FAST_EXP2(D0[r]);                                    \
        hn[r] = fmaf(-2.0f, FAST_RCP(e0 + 1.0f), 1.0f);                       \
        const float e1 = FAST_EXP2(D1[r]);                                    \
        hn[4 + r] = fmaf(-2.0f, FAST_RCP(e1 + 1.0f), 1.0f);                   \
        o = fmaf(hn[r], wos[r], fmaf(hn[4 + r], wos[4 + r], o));              \
    }                                                                         \
    Blo = f16x4{(f16)hn[0], (f16)hn[1], (f16)hn[2], (f16)hn[3]};              \
    Bhi = f16x4{(f16)hn[4], (f16)hn[5], (f16)hn[6], (f16)hn[7]};              \
    o += BCF(__builtin_amdgcn_ds_bpermute(ix16, BCI(o)));                     \
    o += BCF(__builtin_amdgcn_ds_bpermute(ix32, BCI(o)));                     \
    os[T2] = o;                                                               \
} while (0)

#define CHUNK(HC, Q0, Q1, Q2, Q3) do {                                        \
    STEP(0,  (Q0).x); STEP(1,  (Q0).y); STEP(2,  (Q0).z); STEP(3,  (Q0).w);   \
    STEP(4,  (Q1).x); STEP(5,  (Q1).y); STEP(6,  (Q1).z); STEP(7,  (Q1).w);   \
    STEP(8,  (Q2).x); STEP(9,  (Q2).y); STEP(10, (Q2).z); STEP(11, (Q2).w);   \
    STEP(12, (Q3).x); STEP(13, (Q3).y); STEP(14, (Q3).z); STEP(15, (Q3).w);   \
    if (q == 0) {                                                             \
        float4 s0, s1, s2, s3;                                                \
        s0.x = os[0]  + bout; s0.y = os[1]  + bout;                           \
        s0.z = os[2]  + bout; s0.w = os[3]  + bout;                           \
        s1.x = os[4]  + bout; s1.y = os[5]  + bout;                           \
        s1.z = os[6]  + bout; s1.w = os[7]  + bout;                           \
        s2.x = os[8]  + bout; s2.y = os[9]  + bout;                           \
        s2.z = os[10] + bout; s2.w = os[11] + bout;                           \
        s3.x = os[12] + bout; s3.y = os[13] + bout;                           \
        s3.z = os[14] + bout; s3.w = os[15] + bout;                           \
        float4* op = reinterpret_cast<float4*>(og + (HC) * 16);               \
        op[0] = s0; op[1] = s1; op[2] = s2; op[3] = s3;                       \
    }                                                                         \
} while (0)

    // x register double-buffer: 16 steps (4x float4) per chunk
    const float4* xp0 = reinterpret_cast<const float4*>(xg);
    float4 a0 = xp0[0], a1 = xp0[1], a2 = xp0[2], a3 = xp0[3];
    float4 b0, b1, b2, b3;

    #pragma unroll 1
    for (int hc = 0; hc < 32; hc += 2) {
        const float4* pB = reinterpret_cast<const float4*>(xg + (hc + 1) * 16);
        b0 = pB[0]; b1 = pB[1]; b2 = pB[2]; b3 = pB[3];
        CHUNK(hc, a0, a1, a2, a3);
        const int tn = (hc + 2 < 32) ? (hc + 2) : 0;  // clamp: harmless reload
        const float4* pA = reinterpret_cast<const float4*>(xg + tn * 16);
        a0 = pA[0]; a1 = pA[1]; a2 = pA[2]; a3 = pA[3];
        CHUNK(hc + 1, b0, b1, b2, b3);
    }

    // ---- final hidden state [1, B, H]: lane (c,q) owns h = {4q..4q+3} and
    // {16+4q..16+4q+3} of seq c -> two float4 stores, full coverage ----
    float* hp = out + (size_t)BATCH * SEQT + (size_t)seq * HID;
    float4 t0; t0.x = hn[0]; t0.y = hn[1]; t0.z = hn[2]; t0.w = hn[3];
    float4 t1; t1.x = hn[4]; t1.y = hn[5]; t1.z = hn[6]; t1.w = hn[7];
    *reinterpret_cast<float4*>(hp + 4 * q)      = t0;
    *reinterpret_cast<float4*>(hp + 16 + 4 * q) = t1;

#undef CHUNK
#undef STEP
}

extern "C" void kernel_launch(void* const* d_in, const int* in_sizes, int n_in,
                              void* d_out, int out_size, void* d_ws, size_t ws_size,
                              hipStream_t stream) {
    const float* x     = (const float*)d_in[0];
    const float* h0    = (const float*)d_in[1];
    const float* W_ih  = (const float*)d_in[2];
    const float* b_ih  = (const float*)d_in[3];
    const float* W_hh  = (const float*)d_in[4];
    const float* b_hh  = (const float*)d_in[5];
    const float* W_out = (const float*)d_in[6];
    const float* b_out = (const float*)d_in[7];
    float* outp = (float*)d_out;

    dim3 grid(BATCH / 16);   // 256 blocks x 1 wave x 16 seqs/wave
    dim3 block(64);
    hipLaunchKernelGGL(rnn_kernel, grid, block, 0, stream,
                       x, h0, W_ih, b_ih, W_hh, b_hh, W_out, b_out, outp);
}

// Round 8
// 165.170 us; speedup vs baseline: 1.0686x; 1.0686x over previous
//
#include <hip/hip_runtime.h>

#define BATCH 4096
#define SEQT  512
#define HID   32

typedef _Float16 f16;
typedef _Float16 h2    __attribute__((ext_vector_type(2)));
typedef _Float16 f16x4 __attribute__((ext_vector_type(4)));
typedef float    f32x4 __attribute__((ext_vector_type(4)));

// Legacy K=16 MFMA builtins use the NO-underscore spelling (16x16x16f16).
#define MFMA16(a, b, c) __builtin_amdgcn_mfma_f32_16x16x16f16((a), (b), (c), 0, 0, 0)

// cvt_pkrtz returns __fp16x2 -- bit_cast to our _Float16x2 (round-7 fix).
#if __has_builtin(__builtin_amdgcn_cvt_pkrtz)
__device__ __forceinline__ h2 PKRTZ(float a, float b) {
    return __builtin_bit_cast(h2, __builtin_amdgcn_cvt_pkrtz(a, b));
}
#else
__device__ __forceinline__ h2 PKRTZ(float a, float b) { h2 r; r.x = (f16)a; r.y = (f16)b; return r; }
#endif

#if __has_builtin(__builtin_amdgcn_exp2f)
#define FAST_EXP2(x) __builtin_amdgcn_exp2f(x)
#else
#define FAST_EXP2(x) exp2f(x)
#endif
#if __has_builtin(__builtin_amdgcn_rcpf)
#define FAST_RCP(x) __builtin_amdgcn_rcpf(x)
#else
#define FAST_RCP(x) (1.0f / (x))
#endif

#define BCI(f) __builtin_bit_cast(int, (f))
#define BCF(i) __builtin_bit_cast(float, (i))

union f16x4u { f16x4 v; h2 p[2]; };

// MFMA-driven RNN: one wave owns 16 sequences; h-state [32 x 16] lives in MFMA
// B-fragment layout. Recurrence spine: mfma -> mfma -> tanh -> cvt_pkrtz pack
// (D-layout == B-layout for the classic 16x16x16 shape, so no cross-lane remap).
// Round-6 lesson: the per-step ds_bpermute pair put ~240 cy of serial LDS
// latency INSIDE the only wave's chain (523 cy/step measured, VALUBusy 17%).
// Fix: stash lane-local output partials per step; ONE batched cross-lane
// reduce per 16-step chunk (16 independent ^16 bpermutes, then 16 ^32) --
// latency pipelined across values and overlapped with the next chunk's MFMAs
// (the h-chain does not depend on it).
__global__ __launch_bounds__(64, 1) void rnn_kernel(
    const float* __restrict__ x,      // [B, T]
    const float* __restrict__ h0,     // [B, H]
    const float* __restrict__ W_ih,   // [H]
    const float* __restrict__ b_ih,   // [H]
    const float* __restrict__ W_hh,   // [H, H] row-major
    const float* __restrict__ b_hh,   // [H]
    const float* __restrict__ W_out,  // [H]
    const float* __restrict__ b_out,  // [1]
    float* __restrict__ out)          // [B*T] outs, then [B*H] hT
{
    const int lane = threadIdx.x & 63;
    const int c    = lane & 15;            // seq column within tile
    const int q    = lane >> 4;            // 4-row group
    const int seq  = blockIdx.x * 16 + c;

    const float SC = 2.8853900817779268f;  // 2*log2(e), folded into W/b

    // ---- A fragments: A[m][kh], row = 16m + (lane&15), k = 16kh + 4q + e ----
    f16x4 A00, A01, A10, A11;
    {
        const float4 w00 = *reinterpret_cast<const float4*>(W_hh + c * HID + 4 * q);
        const float4 w01 = *reinterpret_cast<const float4*>(W_hh + c * HID + 16 + 4 * q);
        const float4 w10 = *reinterpret_cast<const float4*>(W_hh + (16 + c) * HID + 4 * q);
        const float4 w11 = *reinterpret_cast<const float4*>(W_hh + (16 + c) * HID + 16 + 4 * q);
        A00 = f16x4{(f16)(SC * w00.x), (f16)(SC * w00.y), (f16)(SC * w00.z), (f16)(SC * w00.w)};
        A01 = f16x4{(f16)(SC * w01.x), (f16)(SC * w01.y), (f16)(SC * w01.z), (f16)(SC * w01.w)};
        A10 = f16x4{(f16)(SC * w10.x), (f16)(SC * w10.y), (f16)(SC * w10.z), (f16)(SC * w10.w)};
        A11 = f16x4{(f16)(SC * w11.x), (f16)(SC * w11.y), (f16)(SC * w11.z), (f16)(SC * w11.w)};
    }

    // ---- per-lane params: i = m*4 + r  <->  hidden h = 16m + 4q + r ----
    float wihs[8], biass[8], wos[8];
    #pragma unroll
    for (int m = 0; m < 2; ++m)
        #pragma unroll
        for (int r = 0; r < 4; ++r) {
            const int h = 16 * m + 4 * q + r;
            wihs[m * 4 + r]  = SC * W_ih[h];
            biass[m * 4 + r] = SC * (b_ih[h] + b_hh[h]);
            wos[m * 4 + r]   = W_out[h];
        }
    const float bout = b_out[0];

    // ---- B fragments seeded from h0: k = 16kh + 4q + e, col = c ----
    f16x4 Blo, Bhi;
    {
        const float4 lo = *reinterpret_cast<const float4*>(h0 + (size_t)seq * HID + 4 * q);
        const float4 hi = *reinterpret_cast<const float4*>(h0 + (size_t)seq * HID + 16 + 4 * q);
        Blo = f16x4{(f16)lo.x, (f16)lo.y, (f16)lo.z, (f16)lo.w};
        Bhi = f16x4{(f16)hi.x, (f16)hi.y, (f16)hi.z, (f16)hi.w};
    }

    const float* xg = x + (size_t)seq * SEQT;
    float*       og = out + (size_t)seq * SEQT;

    const int ix16 = (lane ^ 16) << 2;
    const int ix32 = (lane ^ 32) << 2;

    float hn[8];      // f32 post-tanh state (persists for hT)
    float os[16];     // per-chunk lane-local output partials (static indexing)

#define STEP(T2, XC) do {                                                     \
    f32x4 C0, C1;                                                             \
    C0[0] = fmaf((XC), wihs[0], biass[0]);                                    \
    C0[1] = fmaf((XC), wihs[1], biass[1]);                                    \
    C0[2] = fmaf((XC), wihs[2], biass[2]);                                    \
    C0[3] = fmaf((XC), wihs[3], biass[3]);                                    \
    C1[0] = fmaf((XC), wihs[4], biass[4]);                                    \
    C1[1] = fmaf((XC), wihs[5], biass[5]);                                    \
    C1[2] = fmaf((XC), wihs[6], biass[6]);                                    \
    C1[3] = fmaf((XC), wihs[7], biass[7]);                                    \
    f32x4 D0 = MFMA16(A00, Blo, C0);                                          \
    f32x4 D1 = MFMA16(A10, Blo, C1);                                          \
    D0 = MFMA16(A01, Bhi, D0);                                                \
    D1 = MFMA16(A11, Bhi, D1);                                                \
    float o = 0.0f;                                                           \
    _Pragma("unroll")                                                         \
    for (int r = 0; r < 4; ++r) {                                             \
        const float e0 = FAST_EXP2(D0[r]);                                    \
        hn[r] = fmaf(-2.0f, FAST_RCP(e0 + 1.0f), 1.0f);                       \
        const float e1 = FAST_EXP2(D1[r]);                                    \
        hn[4 + r] = fmaf(-2.0f, FAST_RCP(e1 + 1.0f), 1.0f);                   \
        o = fmaf(hn[r], wos[r], fmaf(hn[4 + r], wos[4 + r], o));              \
    }                                                                         \
    f16x4u uL, uH;                                                            \
    uL.p[0] = PKRTZ(hn[0], hn[1]); uL.p[1] = PKRTZ(hn[2], hn[3]);             \
    uH.p[0] = PKRTZ(hn[4], hn[5]); uH.p[1] = PKRTZ(hn[6], hn[7]);             \
    Blo = uL.v; Bhi = uH.v;                                                   \
    os[T2] = o;                                                               \
} while (0)

#define CHUNK(HC, Q0, Q1, Q2, Q3) do {                                        \
    STEP(0,  (Q0).x); STEP(1,  (Q0).y); STEP(2,  (Q0).z); STEP(3,  (Q0).w);   \
    STEP(4,  (Q1).x); STEP(5,  (Q1).y); STEP(6,  (Q1).z); STEP(7,  (Q1).w);   \
    STEP(8,  (Q2).x); STEP(9,  (Q2).y); STEP(10, (Q2).z); STEP(11, (Q2).w);   \
    STEP(12, (Q3).x); STEP(13, (Q3).y); STEP(14, (Q3).z); STEP(15, (Q3).w);   \
    _Pragma("unroll")                                                         \
    for (int t = 0; t < 16; ++t)                                              \
        os[t] += BCF(__builtin_amdgcn_ds_bpermute(ix16, BCI(os[t])));         \
    _Pragma("unroll")                                                         \
    for (int t = 0; t < 16; ++t)                                              \
        os[t] += BCF(__builtin_amdgcn_ds_bpermute(ix32, BCI(os[t])));         \
    if (q == 0) {                                                             \
        float4 s0, s1, s2, s3;                                                \
        s0.x = os[0]  + bout; s0.y = os[1]  + bout;                           \
        s0.z = os[2]  + bout; s0.w = os[3]  + bout;                           \
        s1.x = os[4]  + bout; s1.y = os[5]  + bout;                           \
        s1.z = os[6]  + bout; s1.w = os[7]  + bout;                           \
        s2.x = os[8]  + bout; s2.y = os[9]  + bout;                           \
        s2.z = os[10] + bout; s2.w = os[11] + bout;                           \
        s3.x = os[12] + bout; s3.y = os[13] + bout;                           \
        s3.z = os[14] + bout; s3.w = os[15] + bout;                           \
        float4* op = reinterpret_cast<float4*>(og + (HC) * 16);               \
        op[0] = s0; op[1] = s1; op[2] = s2; op[3] = s3;                       \
    }                                                                         \
} while (0)

    // x register double-buffer: 16 steps (4x float4) per chunk
    const float4* xp0 = reinterpret_cast<const float4*>(xg);
    float4 a0 = xp0[0], a1 = xp0[1], a2 = xp0[2], a3 = xp0[3];
    float4 b0, b1, b2, b3;

    #pragma unroll 1
    for (int hc = 0; hc < 32; hc += 2) {
        const float4* pB = reinterpret_cast<const float4*>(xg + (hc + 1) * 16);
        b0 = pB[0]; b1 = pB[1]; b2 = pB[2]; b3 = pB[3];
        CHUNK(hc, a0, a1, a2, a3);
        const int tn = (hc + 2 < 32) ? (hc + 2) : 0;  // clamp: harmless reload
        const float4* pA = reinterpret_cast<const float4*>(xg + tn * 16);
        a0 = pA[0]; a1 = pA[1]; a2 = pA[2]; a3 = pA[3];
        CHUNK(hc + 1, b0, b1, b2, b3);
    }

    // ---- final hidden state [1, B, H]: lane (c,q) owns h = {4q..4q+3} and
    // {16+4q..16+4q+3} of seq c -> two float4 stores, full coverage ----
    float* hp = out + (size_t)BATCH * SEQT + (size_t)seq * HID;
    float4 t0; t0.x = hn[0]; t0.y = hn[1]; t0.z = hn[2]; t0.w = hn[3];
    float4 t1; t1.x = hn[4]; t1.y = hn[5]; t1.z = hn[6]; t1.w = hn[7];
    *reinterpret_cast<float4*>(hp + 4 * q)      = t0;
    *reinterpret_cast<float4*>(hp + 16 + 4 * q) = t1;

#undef CHUNK
#undef STEP
}

extern "C" void kernel_launch(void* const* d_in, const int* in_sizes, int n_in,
                              void* d_out, int out_size, void* d_ws, size_t ws_size,
                              hipStream_t stream) {
    const float* x     = (const float*)d_in[0];
    const float* h0    = (const float*)d_in[1];
    const float* W_ih  = (const float*)d_in[2];
    const float* b_ih  = (const float*)d_in[3];
    const float* W_hh  = (const float*)d_in[4];
    const float* b_hh  = (const float*)d_in[5];
    const float* W_out = (const float*)d_in[6];
    const float* b_out = (const float*)d_in[7];
    float* outp = (float*)d_out;

    dim3 grid(BATCH / 16);   // 256 blocks x 1 wave x 16 seqs/wave
    dim3 block(64);
    hipLaunchKernelGGL(rnn_kernel, grid, block, 0, stream,
                       x, h0, W_ih, b_ih, W_hh, b_hh, W_out, b_out, outp);
}

// Round 9
// 162.537 us; speedup vs baseline: 1.0859x; 1.0162x over previous
//
#include <hip/hip_runtime.h>

#define BATCH 4096
#define SEQT  512
#define HID   32

typedef _Float16 f16;
typedef _Float16 h2    __attribute__((ext_vector_type(2)));
typedef _Float16 f16x8 __attribute__((ext_vector_type(8)));
typedef float    f32x4 __attribute__((ext_vector_type(4)));

// gfx950-new 2xK MFMA (underscore spelling per verified intrinsic list).
#define MFMA32(a, b, c) __builtin_amdgcn_mfma_f32_16x16x32_f16((a), (b), (c), 0, 0, 0)

// cvt_pkrtz returns __fp16x2 -- bit_cast to our _Float16x2.
#if __has_builtin(__builtin_amdgcn_cvt_pkrtz)
__device__ __forceinline__ h2 PKRTZ(float a, float b) {
    return __builtin_bit_cast(h2, __builtin_amdgcn_cvt_pkrtz(a, b));
}
#else
__device__ __forceinline__ h2 PKRTZ(float a, float b) { h2 r; r.x = (f16)a; r.y = (f16)b; return r; }
#endif

#if __has_builtin(__builtin_amdgcn_exp2f)
#define FAST_EXP2(x) __builtin_amdgcn_exp2f(x)
#else
#define FAST_EXP2(x) exp2f(x)
#endif
#if __has_builtin(__builtin_amdgcn_rcpf)
#define FAST_RCP(x) __builtin_amdgcn_rcpf(x)
#else
#define FAST_RCP(x) (1.0f / (x))
#endif

#define BCI(f) __builtin_bit_cast(int, (f))
#define BCF(i) __builtin_bit_cast(float, (i))

union f16x8u { f16x8 v; h2 p[4]; };

// MFMA RNN, K=32 spine. One wave owns 16 sequences; h-state [32 x 16] in MFMA
// B-fragment layout. Rounds 6-8 established: duration == 512 x per-step chain
// latency (~470 cy); the chain was mfma->mfma(SrcC dep)->tanh->pack. This
// version uses ONE v_mfma_f32_16x16x32_f16 per 16-row output block (the two
// blocks are PARALLEL), halving the MFMA segment of the chain.
// Layout: 2xK operands are two stacked K=16 fragments (m156 tr_b16 addressing:
// +128B for the second block):  A/B elem e -> k = 16*(e>>2) + 4q + (e&3).
// D: col=lane&15, row=4q+r. So D0 (rows 0-15) -> B elems 0-3 and D1 (rows
// 16-31) -> B elems 4-7 DIRECTLY: the D==B pack property survives, still no
// cross-lane traffic in the recurrence.
__global__ __launch_bounds__(64, 1) void rnn_kernel(
    const float* __restrict__ x,      // [B, T]
    const float* __restrict__ h0,     // [B, H]
    const float* __restrict__ W_ih,   // [H]
    const float* __restrict__ b_ih,   // [H]
    const float* __restrict__ W_hh,   // [H, H] row-major
    const float* __restrict__ b_hh,   // [H]
    const float* __restrict__ W_out,  // [H]
    const float* __restrict__ b_out,  // [1]
    float* __restrict__ out)          // [B*T] outs, then [B*H] hT
{
    const int lane = threadIdx.x & 63;
    const int c    = lane & 15;            // seq column within tile
    const int q    = lane >> 4;            // 4-row group
    const int seq  = blockIdx.x * 16 + c;

    const float SC = 2.8853900817779268f;  // 2*log2(e), folded into W/b

    // ---- A fragments (K=32): Atop rows 0-15, Abot rows 16-31.
    // elem e: k = 16*(e>>2) + 4q + (e&3)  => e0-3 from k=4q.., e4-7 from k=16+4q..
    f16x8 Atop, Abot;
    {
        const float4 w00 = *reinterpret_cast<const float4*>(W_hh + c * HID + 4 * q);
        const float4 w01 = *reinterpret_cast<const float4*>(W_hh + c * HID + 16 + 4 * q);
        const float4 w10 = *reinterpret_cast<const float4*>(W_hh + (16 + c) * HID + 4 * q);
        const float4 w11 = *reinterpret_cast<const float4*>(W_hh + (16 + c) * HID + 16 + 4 * q);
        Atop = f16x8{(f16)(SC * w00.x), (f16)(SC * w00.y), (f16)(SC * w00.z), (f16)(SC * w00.w),
                     (f16)(SC * w01.x), (f16)(SC * w01.y), (f16)(SC * w01.z), (f16)(SC * w01.w)};
        Abot = f16x8{(f16)(SC * w10.x), (f16)(SC * w10.y), (f16)(SC * w10.z), (f16)(SC * w10.w),
                     (f16)(SC * w11.x), (f16)(SC * w11.y), (f16)(SC * w11.z), (f16)(SC * w11.w)};
    }

    // ---- per-lane params: i = m*4 + r  <->  hidden h = 16m + 4q + r ----
    float wihs[8], biass[8], wos[8];
    #pragma unroll
    for (int m = 0; m < 2; ++m)
        #pragma unroll
        for (int r = 0; r < 4; ++r) {
            const int h = 16 * m + 4 * q + r;
            wihs[m * 4 + r]  = SC * W_ih[h];
            biass[m * 4 + r] = SC * (b_ih[h] + b_hh[h]);
            wos[m * 4 + r]   = W_out[h];
        }
    const float bout = b_out[0];

    // ---- B fragment seeded from h0: elems 0-3 = h[4q..], elems 4-7 = h[16+4q..]
    f16x8 B;
    {
        const float4 lo = *reinterpret_cast<const float4*>(h0 + (size_t)seq * HID + 4 * q);
        const float4 hi = *reinterpret_cast<const float4*>(h0 + (size_t)seq * HID + 16 + 4 * q);
        B = f16x8{(f16)lo.x, (f16)lo.y, (f16)lo.z, (f16)lo.w,
                  (f16)hi.x, (f16)hi.y, (f16)hi.z, (f16)hi.w};
    }

    const float* xg = x + (size_t)seq * SEQT;
    float*       og = out + (size_t)seq * SEQT;

    const int ix16 = (lane ^ 16) << 2;
    const int ix32 = (lane ^ 32) << 2;

    float hn[8];      // f32 post-tanh state (persists for hT)
    float os[16];     // per-chunk lane-local output partials (static indexing)

#define STEP(T2, XC) do {                                                     \
    f32x4 C0, C1;                                                             \
    C0[0] = fmaf((XC), wihs[0], biass[0]);                                    \
    C0[1] = fmaf((XC), wihs[1], biass[1]);                                    \
    C0[2] = fmaf((XC), wihs[2], biass[2]);                                    \
    C0[3] = fmaf((XC), wihs[3], biass[3]);                                    \
    C1[0] = fmaf((XC), wihs[4], biass[4]);                                    \
    C1[1] = fmaf((XC), wihs[5], biass[5]);                                    \
    C1[2] = fmaf((XC), wihs[6], biass[6]);                                    \
    C1[3] = fmaf((XC), wihs[7], biass[7]);                                    \
    const f32x4 D0 = MFMA32(Atop, B, C0);                                     \
    const f32x4 D1 = MFMA32(Abot, B, C1);                                     \
    float o = 0.0f;                                                           \
    _Pragma("unroll")                                                         \
    for (int r = 0; r < 4; ++r) {                                             \
        const float e0 = FAST_EXP2(D0[r]);                                    \
        hn[r] = fmaf(-2.0f, FAST_RCP(e0 + 1.0f), 1.0f);                       \
        const float e1 = FAST_EXP2(D1[r]);                                    \
        hn[4 + r] = fmaf(-2.0f, FAST_RCP(e1 + 1.0f), 1.0f);                   \
        o = fmaf(hn[r], wos[r], fmaf(hn[4 + r], wos[4 + r], o));              \
    }                                                                         \
    f16x8u uB;                                                                \
    uB.p[0] = PKRTZ(hn[0], hn[1]); uB.p[1] = PKRTZ(hn[2], hn[3]);             \
    uB.p[2] = PKRTZ(hn[4], hn[5]); uB.p[3] = PKRTZ(hn[6], hn[7]);             \
    B = uB.v;                                                                 \
    os[T2] = o;                                                               \
} while (0)

#define CHUNK(HC, Q0, Q1, Q2, Q3) do {                                        \
    STEP(0,  (Q0).x); STEP(1,  (Q0).y); STEP(2,  (Q0).z); STEP(3,  (Q0).w);   \
    STEP(4,  (Q1).x); STEP(5,  (Q1).y); STEP(6,  (Q1).z); STEP(7,  (Q1).w);   \
    STEP(8,  (Q2).x); STEP(9,  (Q2).y); STEP(10, (Q2).z); STEP(11, (Q2).w);   \
    STEP(12, (Q3).x); STEP(13, (Q3).y); STEP(14, (Q3).z); STEP(15, (Q3).w);   \
    _Pragma("unroll")                                                         \
    for (int t = 0; t < 16; ++t)                                              \
        os[t] += BCF(__builtin_amdgcn_ds_bpermute(ix16, BCI(os[t])));         \
    _Pragma("unroll")                                                         \
    for (int t = 0; t < 16; ++t)                                              \
        os[t] += BCF(__builtin_amdgcn_ds_bpermute(ix32, BCI(os[t])));         \
    if (q == 0) {                                                             \
        float4 s0, s1, s2, s3;                                                \
        s0.x = os[0]  + bout; s0.y = os[1]  + bout;                           \
        s0.z = os[2]  + bout; s0.w = os[3]  + bout;                           \
        s1.x = os[4]  + bout; s1.y = os[5]  + bout;                           \
        s1.z = os[6]  + bout; s1.w = os[7]  + bout;                           \
        s2.x = os[8]  + bout; s2.y = os[9]  + bout;                           \
        s2.z = os[10] + bout; s2.w = os[11] + bout;                           \
        s3.x = os[12] + bout; s3.y = os[13] + bout;                           \
        s3.z = os[14] + bout; s3.w = os[15] + bout;                           \
        float4* op = reinterpret_cast<float4*>(og + (HC) * 16);               \
        op[0] = s0; op[1] = s1; op[2] = s2; op[3] = s3;                       \
    }                                                                         \
} while (0)

    // x register double-buffer: 16 steps (4x float4) per chunk
    const float4* xp0 = reinterpret_cast<const float4*>(xg);
    float4 a0 = xp0[0], a1 = xp0[1], a2 = xp0[2], a3 = xp0[3];
    float4 b0, b1, b2, b3;

    #pragma unroll 1
    for (int hc = 0; hc < 32; hc += 2) {
        const float4* pB = reinterpret_cast<const float4*>(xg + (hc + 1) * 16);
        b0 = pB[0]; b1 = pB[1]; b2 = pB[2]; b3 = pB[3];
        CHUNK(hc, a0, a1, a2, a3);
        const int tn = (hc + 2 < 32) ? (hc + 2) : 0;  // clamp: harmless reload
        const float4* pA = reinterpret_cast<const float4*>(xg + tn * 16);
        a0 = pA[0]; a1 = pA[1]; a2 = pA[2]; a3 = pA[3];
        CHUNK(hc + 1, b0, b1, b2, b3);
    }

    // ---- final hidden state [1, B, H]: lane (c,q) owns h = {4q..4q+3} and
    // {16+4q..16+4q+3} of seq c -> two float4 stores, full coverage ----
    float* hp = out + (size_t)BATCH * SEQT + (size_t)seq * HID;
    float4 t0; t0.x = hn[0]; t0.y = hn[1]; t0.z = hn[2]; t0.w = hn[3];
    float4 t1; t1.x = hn[4]; t1.y = hn[5]; t1.z = hn[6]; t1.w = hn[7];
    *reinterpret_cast<float4*>(hp + 4 * q)      = t0;
    *reinterpret_cast<float4*>(hp + 16 + 4 * q) = t1;

#undef CHUNK
#undef STEP
}

extern "C" void kernel_launch(void* const* d_in, const int* in_sizes, int n_in,
                              void* d_out, int out_size, void* d_ws, size_t ws_size,
                              hipStream_t stream) {
    const float* x     = (const float*)d_in[0];
    const float* h0    = (const float*)d_in[1];
    const float* W_ih  = (const float*)d_in[2];
    const float* b_ih  = (const float*)d_in[3];
    const float* W_hh  = (const float*)d_in[4];
    const float* b_hh  = (const float*)d_in[5];
    const float* W_out = (const float*)d_in[6];
    const float* b_out = (const float*)d_in[7];
    float* outp = (float*)d_out;

    dim3 grid(BATCH / 16);   // 256 blocks x 1 wave x 16 seqs/wave
    dim3 block(64);
    hipLaunchKernelGGL(rnn_kernel, grid, block, 0, stream,
                       x, h0, W_ih, b_ih, W_hh, b_hh, W_out, b_out, outp);
}